// Round 4
// baseline (409.083 us; speedup 1.0000x reference)
//
#include <hip/hip_runtime.h>
#include <hip/hip_bf16.h>

typedef unsigned short ushort_t;
typedef unsigned int uint_t;
typedef short bf16x8 __attribute__((ext_vector_type(8)));
typedef float f32x4 __attribute__((ext_vector_type(4)));

#define MFMA16(a, b, c) __builtin_amdgcn_mfma_f32_16x16x32_bf16((a), (b), (c), 0, 0, 0)

// ---------- numeric helpers ----------
__device__ __forceinline__ ushort_t f2bf(float f) {
  uint_t u = __float_as_uint(f);
  u += 0x7fffu + ((u >> 16) & 1u);  // RNE; inputs finite
  return (ushort_t)(u >> 16);
}
__device__ __forceinline__ float bf2f(ushort_t h) {
  return __uint_as_float(((uint_t)h) << 16);
}
__device__ __forceinline__ uint_t pack2(float lo, float hi) {
  union { __hip_bfloat162 h; uint_t u; } cv;
  cv.h = __float22bfloat162_rn(float2{lo, hi});
  return cv.u;
}
__device__ __forceinline__ uint2 pack4(f32x4 v) {
  uint2 o;
  o.x = pack2(v[0], v[1]);
  o.y = pack2(v[2], v[3]);
  return o;
}
__device__ __forceinline__ float eluf(float x) {
  float e = __expf(x) - 1.0f;
  return x > 0.0f ? x : e;
}
__device__ __forceinline__ float sigmf(float x) {
  return 1.0f / (1.0f + __expf(-x));
}
// LDS byte offset for [row][col] bf16 tiles, XOR swizzle on bits 4-6
__device__ __forceinline__ int lds_off(int row, int colb, int ccb) {
  return row * ccb + (colb ^ ((row & 7) << 4));
}

// ---------- sizes / workspace layout (ushort elements) ----------
constexpr size_t OFF_ENCF = 0;       // enc_flat bf16 [32768][128]
constexpr size_t OFF_ENC  = 4194304; // enc bf16 [32768][128]
constexpr size_t OFF_TEFF = 8388608; // total_effect bf16 [32768][64]
constexpr size_t OFF_FR   = 10485760;

// fragment-layout weight offsets (ushort elements, relative to OFF_FR)
constexpr int FR_LE_W1  = 0;        // 128x128
constexpr int FR_LE_W2  = 16384;    // 128x128
constexpr int FR_AE_W2  = 32768;    // 128x64
constexpr int FR_AEF_W1 = 40960;    // 192x128
constexpr int FR_AAT_W1 = 65536;    // 192x128
constexpr int FR_AEF_W2 = 90112;    // 128x128
constexpr int FR_PE_W1  = 106496;   // 256x256
constexpr int FR_PE_W2  = 172032;   // 256x128
constexpr int FR_IE_W1  = 204800;   // 128x128
constexpr int FR_IE_W2  = 221184;   // 128x64
constexpr int FR_IA_W1  = 229376;   // 128x128
constexpr int FR_FM_W1  = 245760;   // 192x128
constexpr int FR_FM_W2  = 270336;   // 128x128

// ---------- weight prep: fp32 (K,N) row-major -> bf16 MFMA W-fragments ----------
// frag f = ntile*(K/32) + kstep; element idx = f*512 + lane*8 + e
// holds W[kstep*32 + (lane>>4)*8 + e][ntile*16 + (lane&15)]
// Used as the A-operand: A[row=n=lane&15][k] = W[k][n]  (i.e. W^T chunk).
struct PrepDesc { const float* src; ushort_t* dst; int K; int N; };
struct PrepArgs { PrepDesc d[13]; };

__global__ __launch_bounds__(256) void prep_kernel(PrepArgs a) {
  PrepDesc p = a.d[blockIdx.y];
  int idx = blockIdx.x * 256 + threadIdx.x;
  if (idx >= p.K * p.N) return;
  int e = idx & 7;
  int lane = (idx >> 3) & 63;
  int f = idx >> 9;
  int ksteps = p.K >> 5;
  int kstep = f % ksteps;
  int ntile = f / ksteps;
  int k = kstep * 32 + ((lane >> 4) << 3) + e;
  int n = ntile * 16 + (lane & 15);
  p.dst[idx] = f2bf(p.src[k * p.N + n]);
}

// ---------- transposed GEMM building blocks ----------
// All layers compute D = Wfrag (A) x Xfrag (B) = (X*W)^T per 16x16 tile.
// X-frag: lane holds X[token = lane&15][k = (lane>>4)*8 + e]
// D:      lane holds out[token = lane&15][feature = (lane>>4)*4 + reg]
// -> features are register-consecutive per lane: pack pairs, ds_write_b64.

template <int MT, int NT, int KS>
__device__ __forceinline__ void reg_gemm_t(const bf16x8 x[MT][KS],
                                           const ushort_t* __restrict__ wfrag,
                                           int ntile0, int lane, f32x4 acc[MT][NT]) {
  const f32x4 z = {0.f, 0.f, 0.f, 0.f};
#pragma unroll
  for (int nt = 0; nt < NT; ++nt) {
#pragma unroll
    for (int m = 0; m < MT; ++m) acc[m][nt] = z;
    const ushort_t* wf = wfrag + (size_t)((ntile0 + nt) * KS) * 512 + lane * 8;
#pragma unroll
    for (int ks = 0; ks < KS; ++ks) {
      bf16x8 wfr = *(const bf16x8*)(wf + ks * 512);
#pragma unroll
      for (int m = 0; m < MT; ++m) acc[m][nt] = MFMA16(wfr, x[m][ks], acc[m][nt]);
    }
  }
}

template <int MT, int NT, int KS>
__device__ __forceinline__ void lds_gemm_t(const ushort_t* __restrict__ Abase,
                                           const ushort_t* __restrict__ wfrag,
                                           int ntile0, int lane, f32x4 acc[MT][NT]) {
  const int r = lane & 15, q = lane >> 4;
  bf16x8 x[MT][KS];
#pragma unroll
  for (int m = 0; m < MT; ++m)
#pragma unroll
    for (int ks = 0; ks < KS; ++ks) {
      int row = m * 16 + r;
      x[m][ks] = *(const bf16x8*)((const char*)Abase + lds_off(row, ks * 64 + q * 16, KS * 64));
    }
  reg_gemm_t<MT, NT, KS>(x, wfrag, ntile0, lane, acc);
}

template <int MT, int NT, bool ELU>
__device__ __forceinline__ void add_bias_act_t(f32x4 acc[MT][NT], const float* __restrict__ bias,
                                               int col0, int lane) {
  const int q = lane >> 4;
#pragma unroll
  for (int nt = 0; nt < NT; ++nt) {
    f32x4 bv = *(const f32x4*)(bias + col0 + nt * 16 + q * 4);
#pragma unroll
    for (int m = 0; m < MT; ++m)
#pragma unroll
      for (int k = 0; k < 4; ++k) {
        float v = acc[m][nt][k] + bv[k];
        acc[m][nt][k] = ELU ? eluf(v) : v;
      }
  }
}

template <int MT, int NT, int CCB>  // CCB = LDS row stride in bytes
__device__ __forceinline__ void store_lds_t(ushort_t* Dbase, int col0, int lane,
                                            const f32x4 acc[MT][NT]) {
  const int r = lane & 15, q = lane >> 4;
#pragma unroll
  for (int m = 0; m < MT; ++m) {
    const int row = m * 16 + r;
#pragma unroll
    for (int nt = 0; nt < NT; ++nt) {
      int colb = (col0 + nt * 16 + q * 4) * 2;
      *(uint2*)((char*)Dbase + lds_off(row, colb, CCB)) = pack4(acc[m][nt]);
    }
  }
}

template <int MT, int NT>
__device__ __forceinline__ void store_global_t(ushort_t* __restrict__ G, int row0, int ncols,
                                               int col0, int lane, const f32x4 acc[MT][NT]) {
  const int r = lane & 15, q = lane >> 4;
#pragma unroll
  for (int m = 0; m < MT; ++m)
#pragma unroll
    for (int nt = 0; nt < NT; ++nt)
      *(uint2*)(G + (size_t)(row0 + m * 16 + r) * ncols + col0 + nt * 16 + q * 4) =
          pack4(acc[m][nt]);
}

// ---------- kernel 1: per-object encoder (le, ae, aef, aat -> enc_flat, enc) ----------
__global__ __launch_bounds__(256, 2) void enc_kernel(
    const float* __restrict__ lambda1, const float* __restrict__ actions,
    const float* __restrict__ le_b1, const float* __restrict__ le_b2,
    const float* __restrict__ ae_W1, const float* __restrict__ ae_b1,
    const float* __restrict__ ae_b2, const float* __restrict__ aef_b1,
    const float* __restrict__ aef_b2, const float* __restrict__ aat_b1,
    const float* __restrict__ aat_W2, const float* __restrict__ aat_b2,
    const ushort_t* __restrict__ fr, ushort_t* __restrict__ encf, ushort_t* __restrict__ enc) {
  __shared__ ushort_t bufA[64 * 128];  // 16 KB
  __shared__ ushort_t bufB[64 * 128];  // 16 KB
  __shared__ ushort_t la[64 * 192];    // 24 KB
  __shared__ float att[64];

  const int t = threadIdx.x, lane = t & 63, w = t >> 6;
  const int r = lane & 15, q = lane >> 4;
  const int rows0 = blockIdx.x * 64;

  // stage lambda1 tile -> bufA (bf16, swizzled, packed 8B writes)
  {
    const int row = t >> 2, c0 = (t & 3) * 32;
    const float4* src = (const float4*)(lambda1 + (size_t)(rows0 + row) * 128 + c0);
#pragma unroll
    for (int j = 0; j < 8; ++j) {
      float4 v = src[j];
      f32x4 vv = {v.x, v.y, v.z, v.w};
      *(uint2*)((char*)bufA + lds_off(row, (c0 + j * 4) * 2, 256)) = pack4(vv);
    }
  }
  __syncthreads();

  f32x4 acc2[4][2];
  // le layer 1: bufA -> bufB
  lds_gemm_t<4, 2, 4>(bufA, fr + FR_LE_W1, w * 2, lane, acc2);
  add_bias_act_t<4, 2, true>(acc2, le_b1, w * 32, lane);
  store_lds_t<4, 2, 256>(bufB, w * 32, lane, acc2);
  __syncthreads();
  // le layer 2: bufB -> la[:,0:128] + global enc_flat
  lds_gemm_t<4, 2, 4>(bufB, fr + FR_LE_W2, w * 2, lane, acc2);
  add_bias_act_t<4, 2, true>(acc2, le_b2, w * 32, lane);
  store_lds_t<4, 2, 384>(la, w * 32, lane, acc2);
  store_global_t<4, 2>(encf, rows0, 128, w * 32, lane, acc2);
  // ae layer 1 (K=6, VALU): actions -> bufA (bufA free after prior sync)
  {
    const int row = t >> 2, c0 = (t & 3) * 32;
    float a6[6];
#pragma unroll
    for (int k2 = 0; k2 < 6; ++k2) a6[k2] = actions[(size_t)(rows0 + row) * 6 + k2];
#pragma unroll
    for (int j = 0; j < 16; ++j) {
      int c = c0 + j * 2;
      float s0 = ae_b1[c], s1 = ae_b1[c + 1];
#pragma unroll
      for (int k2 = 0; k2 < 6; ++k2) {
        s0 += a6[k2] * ae_W1[k2 * 128 + c];
        s1 += a6[k2] * ae_W1[k2 * 128 + c + 1];
      }
      *(uint_t*)((char*)bufA + lds_off(row, c * 2, 256)) = pack2(eluf(s0), eluf(s1));
    }
  }
  __syncthreads();
  // ae layer 2: bufA -> la[:,128:192]
  {
    f32x4 acc1[4][1];
    lds_gemm_t<4, 1, 4>(bufA, fr + FR_AE_W2, w, lane, acc1);
    add_bias_act_t<4, 1, true>(acc1, ae_b2, w * 16, lane);
    store_lds_t<4, 1, 384>(la, 128 + w * 16, lane, acc1);
  }
  __syncthreads();
  // aef layer 1: la -> bufA ; aat layer 1: la -> bufB
  lds_gemm_t<4, 2, 6>(la, fr + FR_AEF_W1, w * 2, lane, acc2);
  add_bias_act_t<4, 2, true>(acc2, aef_b1, w * 32, lane);
  store_lds_t<4, 2, 256>(bufA, w * 32, lane, acc2);
  lds_gemm_t<4, 2, 6>(la, fr + FR_AAT_W1, w * 2, lane, acc2);
  add_bias_act_t<4, 2, true>(acc2, aat_b1, w * 32, lane);
  store_lds_t<4, 2, 256>(bufB, w * 32, lane, acc2);
  __syncthreads();
  // aef layer 2: bufA -> regs (a_eff)
  lds_gemm_t<4, 2, 4>(bufA, fr + FR_AEF_W2, w * 2, lane, acc2);
  add_bias_act_t<4, 2, true>(acc2, aef_b2, w * 32, lane);
  // aat layer 2 (N=1, VALU): bufB -> att
  {
    const int row = t >> 2, s = t & 3;
    float sum = 0.f;
#pragma unroll
    for (int j = 0; j < 32; ++j) {
      int c = s * 32 + j;
      sum += bf2f(*(const ushort_t*)((const char*)bufB + lds_off(row, c * 2, 256))) * aat_W2[c];
    }
    sum += __shfl_xor(sum, 1);
    sum += __shfl_xor(sum, 2);
    if (s == 0) att[row] = sigmf(sum + aat_b2[0]);
  }
  __syncthreads();
  // enc = a_eff * a_att -> global (packed 8B stores)
#pragma unroll
  for (int mt = 0; mt < 4; ++mt) {
    float av = att[mt * 16 + r];
#pragma unroll
    for (int nt = 0; nt < 2; ++nt) {
      f32x4 sv = acc2[mt][nt];
      sv[0] *= av; sv[1] *= av; sv[2] *= av; sv[3] *= av;
      *(uint2*)(enc + (size_t)(rows0 + mt * 16 + r) * 128 + w * 32 + nt * 16 + q * 4) = pack4(sv);
    }
  }
}

// ---------- kernel 2: pairwise stage (pe, ie, ia, attention-weighted sum over j) ----------
// Block = 2 groups (b,i), tokens = 32 = all 16 j's per group (j==i masked in reduce).
__global__ __launch_bounds__(256, 3) void pair_kernel(
    const ushort_t* __restrict__ enc, const ushort_t* __restrict__ fr,
    const float* __restrict__ pe_b1, const float* __restrict__ pe_b2,
    const float* __restrict__ ie_b1, const float* __restrict__ ie_b2,
    const float* __restrict__ ia_b1, const float* __restrict__ ia_W2,
    const float* __restrict__ ia_b2, ushort_t* __restrict__ teff) {
  __shared__ ushort_t bufH[32 * 256];   // 16 KB (h_pe; later h_ie | h_ia)
  __shared__ ushort_t bufPi[32 * 128];  // 8 KB
  __shared__ float att[32];

  const int t = threadIdx.x, lane = t & 63, w = t >> 6;
  const int r = lane & 15, q = lane >> 4;
  const int g0 = blockIdx.x * 2;
  const int b = g0 >> 4;

  // pe layer-1 X-fragments straight from global enc
  bf16x8 x[2][8];
#pragma unroll
  for (int mt = 0; mt < 2; ++mt) {
    const int im = (g0 + mt) & 15;
#pragma unroll
    for (int ks = 0; ks < 8; ++ks) {
      const int srow = (ks < 4) ? im : r;  // k 0..127 sender (i), 128..255 receiver (j=token)
      const int k = (ks & 3) * 32 + q * 8;
      x[mt][ks] = *(const bf16x8*)(enc + (size_t)(b * 16 + srow) * 128 + k);
    }
  }
  // pe1: 32 tokens x 256 feats (wave covers 64 feats)
  {
    f32x4 acc[2][4];
    reg_gemm_t<2, 4, 8>(x, fr + FR_PE_W1, w * 4, lane, acc);
    add_bias_act_t<2, 4, true>(acc, pe_b1, w * 64, lane);
    store_lds_t<2, 4, 512>(bufH, w * 64, lane, acc);
  }
  __syncthreads();
  // pe2 -> pi
  {
    f32x4 acc[2][2];
    lds_gemm_t<2, 2, 8>(bufH, fr + FR_PE_W2, w * 2, lane, acc);
    add_bias_act_t<2, 2, true>(acc, pe_b2, w * 32, lane);
    store_lds_t<2, 2, 256>(bufPi, w * 32, lane, acc);
  }
  __syncthreads();
  // ie1 + ia1: pi -> h_ie | h_ia
  {
    f32x4 acc[2][2];
    lds_gemm_t<2, 2, 4>(bufPi, fr + FR_IE_W1, w * 2, lane, acc);
    add_bias_act_t<2, 2, true>(acc, ie_b1, w * 32, lane);
    store_lds_t<2, 2, 256>(bufH, w * 32, lane, acc);
    lds_gemm_t<2, 2, 4>(bufPi, fr + FR_IA_W1, w * 2, lane, acc);
    add_bias_act_t<2, 2, true>(acc, ia_b1, w * 32, lane);
    store_lds_t<2, 2, 256>(bufH + 32 * 128, w * 32, lane, acc);
  }
  __syncthreads();
  // ie2: h_ie -> effect (regs; token=lane&15, feat n2 = w*16+q*4+k)
  f32x4 eff[2][1];
  lds_gemm_t<2, 1, 4>(bufH, fr + FR_IE_W2, w, lane, eff);
  add_bias_act_t<2, 1, true>(eff, ie_b2, w * 16, lane);
  // ia2 (N=1, VALU): h_ia . ia_W2 -> att
  {
    const int row = t >> 3, s = t & 7;
    const char* hia = (const char*)(bufH + 32 * 128);
    float sum = 0.f;
#pragma unroll
    for (int j = 0; j < 16; ++j) {
      int c = s * 16 + j;
      sum += bf2f(*(const ushort_t*)(hia + lds_off(row, c * 2, 256))) * ia_W2[c];
    }
    sum += __shfl_xor(sum, 1);
    sum += __shfl_xor(sum, 2);
    sum += __shfl_xor(sum, 4);
    if (s == 0) att[row] = sigmf(sum + ia_b2[0]);
  }
  __syncthreads();
  // total_effect[g] = sum_{j != i} effect[j] * att[j]   (j = lane&15)
#pragma unroll
  for (int mt = 0; mt < 2; ++mt) {
    const int im = (g0 + mt) & 15;
    const float av = (r == im) ? 0.f : att[mt * 16 + r];
    float v0 = eff[mt][0][0] * av, v1 = eff[mt][0][1] * av;
    float v2 = eff[mt][0][2] * av, v3 = eff[mt][0][3] * av;
#pragma unroll
    for (int d = 1; d < 16; d <<= 1) {
      v0 += __shfl_xor(v0, d);
      v1 += __shfl_xor(v1, d);
      v2 += __shfl_xor(v2, d);
      v3 += __shfl_xor(v3, d);
    }
    if (r == 0) {
      uint2 p;
      p.x = pack2(v0, v1);
      p.y = pack2(v2, v3);
      *(uint2*)(teff + (size_t)(g0 + mt) * 64 + w * 16 + q * 4) = p;
    }
  }
}

// ---------- kernel 3: final merge (fm) -> fp32 output ----------
__global__ __launch_bounds__(256, 2) void fm_kernel(
    const ushort_t* __restrict__ encf, const ushort_t* __restrict__ teff,
    const ushort_t* __restrict__ fr, const float* __restrict__ fm_b1,
    const float* __restrict__ fm_b2, float* __restrict__ out) {
  __shared__ ushort_t bufH[64 * 128];  // 16 KB
  const int t = threadIdx.x, lane = t & 63, w = t >> 6;
  const int r = lane & 15, q = lane >> 4;
  const int rows0 = blockIdx.x * 64;

  bf16x8 x[4][6];
#pragma unroll
  for (int mt = 0; mt < 4; ++mt) {
    const size_t row = rows0 + mt * 16 + r;
#pragma unroll
    for (int ks = 0; ks < 6; ++ks) {
      x[mt][ks] = (ks < 4) ? *(const bf16x8*)(encf + row * 128 + ks * 32 + q * 8)
                           : *(const bf16x8*)(teff + row * 64 + (ks - 4) * 32 + q * 8);
    }
  }
  f32x4 acc[4][2];
  reg_gemm_t<4, 2, 6>(x, fr + FR_FM_W1, w * 2, lane, acc);
  add_bias_act_t<4, 2, true>(acc, fm_b1, w * 32, lane);
  store_lds_t<4, 2, 256>(bufH, w * 32, lane, acc);
  __syncthreads();
  lds_gemm_t<4, 2, 4>(bufH, fr + FR_FM_W2, w * 2, lane, acc);
  add_bias_act_t<4, 2, false>(acc, fm_b2, w * 32, lane);
#pragma unroll
  for (int mt = 0; mt < 4; ++mt)
#pragma unroll
    for (int nt = 0; nt < 2; ++nt)
      *(f32x4*)(out + (size_t)(rows0 + mt * 16 + r) * 128 + w * 32 + nt * 16 + q * 4) =
          acc[mt][nt];
}

// ---------- launcher ----------
extern "C" void kernel_launch(void* const* d_in, const int* in_sizes, int n_in,
                              void* d_out, int out_size, void* d_ws, size_t ws_size,
                              hipStream_t stream) {
  (void)in_sizes; (void)n_in; (void)out_size; (void)ws_size;
  const float* lambda1 = (const float*)d_in[0];
  const float* actions = (const float*)d_in[1];

  ushort_t* ws = (ushort_t*)d_ws;
  ushort_t* encf = ws + OFF_ENCF;
  ushort_t* enc  = ws + OFF_ENC;
  ushort_t* teff = ws + OFF_TEFF;
  ushort_t* fr   = ws + OFF_FR;

  // weight prep (fragment repack, fp32 -> bf16)
  PrepArgs pa;
  const int src_idx[13] = {2, 4, 8, 10, 14, 12, 18, 20, 22, 24, 26, 30, 32};
  const int foff[13] = {FR_LE_W1, FR_LE_W2, FR_AE_W2, FR_AEF_W1, FR_AAT_W1, FR_AEF_W2,
                        FR_PE_W1, FR_PE_W2, FR_IE_W1, FR_IE_W2, FR_IA_W1, FR_FM_W1, FR_FM_W2};
  const int Ks[13] = {128, 128, 128, 192, 192, 128, 256, 256, 128, 128, 128, 192, 128};
  const int Ns[13] = {128, 128, 64, 128, 128, 128, 256, 128, 128, 64, 128, 128, 128};
  for (int i = 0; i < 13; ++i) {
    pa.d[i].src = (const float*)d_in[src_idx[i]];
    pa.d[i].dst = fr + foff[i];
    pa.d[i].K = Ks[i];
    pa.d[i].N = Ns[i];
  }
  prep_kernel<<<dim3(256, 13), 256, 0, stream>>>(pa);

  enc_kernel<<<512, 256, 0, stream>>>(
      lambda1, actions,
      (const float*)d_in[3], (const float*)d_in[5],              // le_b1, le_b2
      (const float*)d_in[6], (const float*)d_in[7],              // ae_W1, ae_b1
      (const float*)d_in[9],                                     // ae_b2
      (const float*)d_in[11], (const float*)d_in[13],            // aef_b1, aef_b2
      (const float*)d_in[15], (const float*)d_in[16],            // aat_b1, aat_W2
      (const float*)d_in[17],                                    // aat_b2
      fr, encf, enc);

  pair_kernel<<<16384, 256, 0, stream>>>(
      enc, fr,
      (const float*)d_in[19], (const float*)d_in[21],            // pe_b1, pe_b2
      (const float*)d_in[23], (const float*)d_in[25],            // ie_b1, ie_b2
      (const float*)d_in[27], (const float*)d_in[28],            // ia_b1, ia_W2
      (const float*)d_in[29],                                    // ia_b2
      teff);

  fm_kernel<<<512, 256, 0, stream>>>(encf, teff, fr,
                                     (const float*)d_in[31], (const float*)d_in[33],
                                     (float*)d_out);
}

// Round 6
// 392.061 us; speedup vs baseline: 1.0434x; 1.0434x over previous
//
#include <hip/hip_runtime.h>
#include <hip/hip_bf16.h>

typedef unsigned short ushort_t;
typedef unsigned int uint_t;
typedef short bf16x8 __attribute__((ext_vector_type(8)));
typedef float f32x4 __attribute__((ext_vector_type(4)));

#define MFMA16(a, b, c) __builtin_amdgcn_mfma_f32_16x16x32_bf16((a), (b), (c), 0, 0, 0)

// ---------- numeric helpers ----------
__device__ __forceinline__ ushort_t f2bf(float f) {
  uint_t u = __float_as_uint(f);
  u += 0x7fffu + ((u >> 16) & 1u);  // RNE; inputs finite
  return (ushort_t)(u >> 16);
}
__device__ __forceinline__ float bf2f(ushort_t h) {
  return __uint_as_float(((uint_t)h) << 16);
}
__device__ __forceinline__ uint_t pack2(float lo, float hi) {
  union { __hip_bfloat162 h; uint_t u; } cv;
  cv.h = __float22bfloat162_rn(float2{lo, hi});
  return cv.u;
}
__device__ __forceinline__ uint2 pack4(f32x4 v) {
  uint2 o;
  o.x = pack2(v[0], v[1]);
  o.y = pack2(v[2], v[3]);
  return o;
}
__device__ __forceinline__ float eluf(float x) {
  float e = __expf(x) - 1.0f;
  return x > 0.0f ? x : e;
}
__device__ __forceinline__ float sigmf(float x) {
  return 1.0f / (1.0f + __expf(-x));
}
// LDS byte offset for [row][col] bf16 tiles, XOR swizzle on bits 4-6
__device__ __forceinline__ int lds_off(int row, int colb, int ccb) {
  return row * ccb + (colb ^ ((row & 7) << 4));
}

// ---------- workspace layout (ushort elements) ----------
constexpr size_t OFF_ENCF = 0;        // enc_flat bf16 [32768][128]
constexpr size_t OFF_ENC  = 4194304;  // enc bf16 [32768][128]
constexpr size_t OFF_TEFF = 8388608;  // total_effect bf16 [32768][64]
constexpr size_t OFF_FR   = 10485760; // weight fragments (286720)
constexpr size_t OFF_U    = 10772480; // U bf16 [32768][256]
constexpr size_t OFF_V    = 19161088; // V bf16 [32768][256]  (end 27549696 us = 55.1 MB)

// fragment-layout weight offsets (ushort elements, relative to OFF_FR)
constexpr int FR_LE_W1  = 0;        // 128x128
constexpr int FR_LE_W2  = 16384;    // 128x128
constexpr int FR_AE_W2  = 32768;    // 128x64
constexpr int FR_AEF_W1 = 40960;    // 192x128
constexpr int FR_AAT_W1 = 65536;    // 192x128
constexpr int FR_AEF_W2 = 90112;    // 128x128
constexpr int FR_PE_W1  = 106496;   // 256x256
constexpr int FR_PE_W2  = 172032;   // 256x128
constexpr int FR_IE_W1  = 204800;   // 128x128
constexpr int FR_IE_W2  = 221184;   // 128x64
constexpr int FR_IA_W1  = 229376;   // 128x128
constexpr int FR_FM_W1  = 245760;   // 192x128
constexpr int FR_FM_W2  = 270336;   // 128x128

// ---------- weight prep: fp32 (K,N) row-major -> bf16 MFMA W-fragments ----------
// frag f = ntile*(K/32) + kstep; element idx = f*512 + lane*8 + e
// holds W[kstep*32 + (lane>>4)*8 + e][ntile*16 + (lane&15)]
struct PrepDesc { const float* src; ushort_t* dst; int K; int N; };
struct PrepArgs { PrepDesc d[13]; };

__global__ __launch_bounds__(256) void prep_kernel(PrepArgs a) {
  PrepDesc p = a.d[blockIdx.y];
  int idx = blockIdx.x * 256 + threadIdx.x;
  if (idx >= p.K * p.N) return;
  int e = idx & 7;
  int lane = (idx >> 3) & 63;
  int f = idx >> 9;
  int ksteps = p.K >> 5;
  int kstep = f % ksteps;
  int ntile = f / ksteps;
  int k = kstep * 32 + ((lane >> 4) << 3) + e;
  int n = ntile * 16 + (lane & 15);
  p.dst[idx] = f2bf(p.src[k * p.N + n]);
}

// ---------- transposed GEMM building blocks ----------
// D = Wfrag (A) x Xfrag (B): lane holds out[token = lane&15][feat = (lane>>4)*4 + reg]

template <int MT, int NT, int KS, int KSTR = KS>
__device__ __forceinline__ void reg_gemm_t(const bf16x8 x[MT][KS],
                                           const ushort_t* __restrict__ wfrag,
                                           int ntile0, int lane, f32x4 acc[MT][NT]) {
  const f32x4 z = {0.f, 0.f, 0.f, 0.f};
#pragma unroll
  for (int nt = 0; nt < NT; ++nt) {
#pragma unroll
    for (int m = 0; m < MT; ++m) acc[m][nt] = z;
    const ushort_t* wf = wfrag + (size_t)((ntile0 + nt) * KSTR) * 512 + lane * 8;
#pragma unroll
    for (int ks = 0; ks < KS; ++ks) {
      bf16x8 wfr = *(const bf16x8*)(wf + ks * 512);
#pragma unroll
      for (int m = 0; m < MT; ++m) acc[m][nt] = MFMA16(wfr, x[m][ks], acc[m][nt]);
    }
  }
}

template <int MT, int KS>
__device__ __forceinline__ void lds_load_x(const ushort_t* __restrict__ Abase, int lane,
                                           bf16x8 x[MT][KS]) {
  const int r = lane & 15, q = lane >> 4;
#pragma unroll
  for (int m = 0; m < MT; ++m)
#pragma unroll
    for (int ks = 0; ks < KS; ++ks) {
      int row = m * 16 + r;
      x[m][ks] = *(const bf16x8*)((const char*)Abase + lds_off(row, ks * 64 + q * 16, KS * 64));
    }
}

template <int MT, int NT, int KS>
__device__ __forceinline__ void lds_gemm_t(const ushort_t* __restrict__ Abase,
                                           const ushort_t* __restrict__ wfrag,
                                           int ntile0, int lane, f32x4 acc[MT][NT]) {
  bf16x8 x[MT][KS];
  lds_load_x<MT, KS>(Abase, lane, x);
  reg_gemm_t<MT, NT, KS>(x, wfrag, ntile0, lane, acc);
}

template <int MT, int NT, bool ELU>
__device__ __forceinline__ void add_bias_act_t(f32x4 acc[MT][NT], const float* __restrict__ bias,
                                               int col0, int lane) {
  const int q = lane >> 4;
#pragma unroll
  for (int nt = 0; nt < NT; ++nt) {
    f32x4 bv = *(const f32x4*)(bias + col0 + nt * 16 + q * 4);
#pragma unroll
    for (int m = 0; m < MT; ++m)
#pragma unroll
      for (int k = 0; k < 4; ++k) {
        float v = acc[m][nt][k] + bv[k];
        acc[m][nt][k] = ELU ? eluf(v) : v;
      }
  }
}

template <int MT, int NT, int CCB>  // CCB = LDS row stride in bytes
__device__ __forceinline__ void store_lds_t(ushort_t* Dbase, int col0, int lane,
                                            const f32x4 acc[MT][NT]) {
  const int r = lane & 15, q = lane >> 4;
#pragma unroll
  for (int m = 0; m < MT; ++m) {
    const int row = m * 16 + r;
#pragma unroll
    for (int nt = 0; nt < NT; ++nt) {
      int colb = (col0 + nt * 16 + q * 4) * 2;
      *(uint2*)((char*)Dbase + lds_off(row, colb, CCB)) = pack4(acc[m][nt]);
    }
  }
}

template <int MT, int NT>
__device__ __forceinline__ void store_global_t(ushort_t* __restrict__ G, int row0, int ncols,
                                               int col0, int lane, const f32x4 acc[MT][NT]) {
  const int r = lane & 15, q = lane >> 4;
#pragma unroll
  for (int m = 0; m < MT; ++m)
#pragma unroll
    for (int nt = 0; nt < NT; ++nt)
      *(uint2*)(G + (size_t)(row0 + m * 16 + r) * ncols + col0 + nt * 16 + q * 4) =
          pack4(acc[m][nt]);
}

// ---------- kernel 1: per-object encoder (le, ae, aef, aat -> enc_flat, enc) ----------
__global__ __launch_bounds__(256, 2) void enc_kernel(
    const float* __restrict__ lambda1, const float* __restrict__ actions,
    const float* __restrict__ le_b1, const float* __restrict__ le_b2,
    const float* __restrict__ ae_W1, const float* __restrict__ ae_b1,
    const float* __restrict__ ae_b2, const float* __restrict__ aef_b1,
    const float* __restrict__ aef_b2, const float* __restrict__ aat_b1,
    const float* __restrict__ aat_W2, const float* __restrict__ aat_b2,
    const ushort_t* __restrict__ fr, ushort_t* __restrict__ encf, ushort_t* __restrict__ enc) {
  __shared__ __align__(16) ushort_t bufA[64 * 128];  // 16 KB
  __shared__ __align__(16) ushort_t bufB[64 * 128];  // 16 KB
  __shared__ __align__(16) ushort_t la[64 * 192];    // 24 KB
  __shared__ float att[64];

  const int t = threadIdx.x, lane = t & 63, w = t >> 6;
  const int r = lane & 15, q = lane >> 4;
  const int rows0 = blockIdx.x * 64;

  // stage lambda1 tile -> bufA (bf16, swizzled, packed 8B writes)
  {
    const int row = t >> 2, c0 = (t & 3) * 32;
    const float4* src = (const float4*)(lambda1 + (size_t)(rows0 + row) * 128 + c0);
#pragma unroll
    for (int j = 0; j < 8; ++j) {
      float4 v = src[j];
      f32x4 vv = {v.x, v.y, v.z, v.w};
      *(uint2*)((char*)bufA + lds_off(row, (c0 + j * 4) * 2, 256)) = pack4(vv);
    }
  }
  __syncthreads();

  f32x4 acc2[4][2];
  // le layer 1: bufA -> bufB
  lds_gemm_t<4, 2, 4>(bufA, fr + FR_LE_W1, w * 2, lane, acc2);
  add_bias_act_t<4, 2, true>(acc2, le_b1, w * 32, lane);
  store_lds_t<4, 2, 256>(bufB, w * 32, lane, acc2);
  __syncthreads();
  // le layer 2: bufB -> la[:,0:128] + global enc_flat
  lds_gemm_t<4, 2, 4>(bufB, fr + FR_LE_W2, w * 2, lane, acc2);
  add_bias_act_t<4, 2, true>(acc2, le_b2, w * 32, lane);
  store_lds_t<4, 2, 384>(la, w * 32, lane, acc2);
  store_global_t<4, 2>(encf, rows0, 128, w * 32, lane, acc2);
  // ae layer 1 (K=6, VALU): actions -> bufA (bufA free after prior sync)
  {
    const int row = t >> 2, c0 = (t & 3) * 32;
    float a6[6];
#pragma unroll
    for (int k2 = 0; k2 < 6; ++k2) a6[k2] = actions[(size_t)(rows0 + row) * 6 + k2];
#pragma unroll
    for (int j = 0; j < 16; ++j) {
      int c = c0 + j * 2;
      float s0 = ae_b1[c], s1 = ae_b1[c + 1];
#pragma unroll
      for (int k2 = 0; k2 < 6; ++k2) {
        s0 += a6[k2] * ae_W1[k2 * 128 + c];
        s1 += a6[k2] * ae_W1[k2 * 128 + c + 1];
      }
      *(uint_t*)((char*)bufA + lds_off(row, c * 2, 256)) = pack2(eluf(s0), eluf(s1));
    }
  }
  __syncthreads();
  // ae layer 2: bufA -> la[:,128:192]
  {
    f32x4 acc1[4][1];
    lds_gemm_t<4, 1, 4>(bufA, fr + FR_AE_W2, w, lane, acc1);
    add_bias_act_t<4, 1, true>(acc1, ae_b2, w * 16, lane);
    store_lds_t<4, 1, 384>(la, 128 + w * 16, lane, acc1);
  }
  __syncthreads();
  // aef layer 1 + aat layer 1: shared A-fragments from la
  {
    bf16x8 xla[4][6];
    lds_load_x<4, 6>(la, lane, xla);
    reg_gemm_t<4, 2, 6>(xla, fr + FR_AEF_W1, w * 2, lane, acc2);
    add_bias_act_t<4, 2, true>(acc2, aef_b1, w * 32, lane);
    store_lds_t<4, 2, 256>(bufA, w * 32, lane, acc2);
    reg_gemm_t<4, 2, 6>(xla, fr + FR_AAT_W1, w * 2, lane, acc2);
    add_bias_act_t<4, 2, true>(acc2, aat_b1, w * 32, lane);
    store_lds_t<4, 2, 256>(bufB, w * 32, lane, acc2);
  }
  __syncthreads();
  // aef layer 2: bufA -> regs (a_eff)
  lds_gemm_t<4, 2, 4>(bufA, fr + FR_AEF_W2, w * 2, lane, acc2);
  add_bias_act_t<4, 2, true>(acc2, aef_b2, w * 32, lane);
  // aat layer 2 (N=1, VALU): bufB -> att
  {
    const int row = t >> 2, s = t & 3;
    float sum = 0.f;
#pragma unroll
    for (int j = 0; j < 32; ++j) {
      int c = s * 32 + j;
      sum += bf2f(*(const ushort_t*)((const char*)bufB + lds_off(row, c * 2, 256))) * aat_W2[c];
    }
    sum += __shfl_xor(sum, 1);
    sum += __shfl_xor(sum, 2);
    if (s == 0) att[row] = sigmf(sum + aat_b2[0]);
  }
  __syncthreads();
  // enc = a_eff * a_att -> global (packed 8B stores)
#pragma unroll
  for (int mt = 0; mt < 4; ++mt) {
    float av = att[mt * 16 + r];
#pragma unroll
    for (int nt = 0; nt < 2; ++nt) {
      f32x4 sv = acc2[mt][nt];
      sv[0] *= av; sv[1] *= av; sv[2] *= av; sv[3] *= av;
      *(uint2*)(enc + (size_t)(rows0 + mt * 16 + r) * 128 + w * 32 + nt * 16 + q * 4) = pack4(sv);
    }
  }
}

// ---------- kernel 2: U/V projections  U = enc @ peW1[:128], V = enc @ peW1[128:] ----------
__global__ __launch_bounds__(256, 2) void uv_kernel(const ushort_t* __restrict__ enc,
                                                    const ushort_t* __restrict__ fr,
                                                    ushort_t* __restrict__ U,
                                                    ushort_t* __restrict__ V) {
  const int t = threadIdx.x, lane = t & 63, w = t >> 6;
  const int r = lane & 15, q = lane >> 4;
  const int rows0 = blockIdx.x * 64;
  const int half = blockIdx.y;  // 0 = U (k rows 0-127), 1 = V (k rows 128-255)

  bf16x8 x[4][4];
#pragma unroll
  for (int m = 0; m < 4; ++m)
#pragma unroll
    for (int ks = 0; ks < 4; ++ks)
      x[m][ks] = *(const bf16x8*)(enc + (size_t)(rows0 + m * 16 + r) * 128 + ks * 32 + q * 8);

  f32x4 acc[4][4];
  // KSTR=8: pe_W1 has K=256 (8 ksteps per ntile); offset ks0 = half*4 folded into pointer
  reg_gemm_t<4, 4, 4, 8>(x, fr + FR_PE_W1 + half * 4 * 512, w * 4, lane, acc);
  store_global_t<4, 4>(half ? V : U, rows0, 256, w * 64, lane, acc);
}

// ---------- kernel 3: pairwise stage (hidden=elu(U[i]+V[j]+b), pe2, ie, ia, reduce) ----------
// Block = 2 groups (b,i); tokens = 32 = all 16 j's per group (j==i masked in reduce).
__global__ __launch_bounds__(256, 4) void pair_kernel(
    const ushort_t* __restrict__ U, const ushort_t* __restrict__ V,
    const ushort_t* __restrict__ fr,
    const float* __restrict__ pe_b1, const float* __restrict__ pe_b2,
    const float* __restrict__ ie_b1, const float* __restrict__ ie_b2,
    const float* __restrict__ ia_b1, const float* __restrict__ ia_W2,
    const float* __restrict__ ia_b2, ushort_t* __restrict__ teff) {
  __shared__ __align__(16) ushort_t hid[32 * 256];   // 16 KB (pe1 hidden; later h_ie | h_ia)
  __shared__ __align__(16) ushort_t bufPi[32 * 128]; // 8 KB
  __shared__ float att[32];

  const int t = threadIdx.x, lane = t & 63, w = t >> 6;
  const int r = lane & 15, q = lane >> 4;
  // bijective XCD swizzle: the 8 blocks of one batch land on one XCD (V-row L2 reuse)
  const int orig = ((blockIdx.x & 7) << 11) + (blockIdx.x >> 3);
  const int g0 = orig * 2;
  const int b = g0 >> 4;

  // stage H: hidden[token][c] = elu(U[i(token)][c] + V[j(token)][c] + pe_b1[c])
  {
    const int token = t >> 3, c0 = (t & 7) * 32;
    const int im = (g0 + (token >> 4)) & 15;
    const ushort_t* Ur = U + (size_t)(b * 16 + im) * 256 + c0;
    const ushort_t* Vr = V + (size_t)(b * 16 + (token & 15)) * 256 + c0;
    const float* bp = pe_b1 + c0;
#pragma unroll
    for (int j4 = 0; j4 < 4; ++j4) {
      bf16x8 uu = *(const bf16x8*)(Ur + j4 * 8);
      bf16x8 vv = *(const bf16x8*)(Vr + j4 * 8);
      f32x4 b0 = *(const f32x4*)(bp + j4 * 8);
      f32x4 b1 = *(const f32x4*)(bp + j4 * 8 + 4);
      float h[8];
#pragma unroll
      for (int e = 0; e < 8; ++e) {
        float bb = (e < 4) ? b0[e] : b1[e - 4];
        h[e] = eluf(bf2f((ushort_t)uu[e]) + bf2f((ushort_t)vv[e]) + bb);
      }
      uint4 pk;
      pk.x = pack2(h[0], h[1]); pk.y = pack2(h[2], h[3]);
      pk.z = pack2(h[4], h[5]); pk.w = pack2(h[6], h[7]);
      *(uint4*)((char*)hid + lds_off(token, (c0 + j4 * 8) * 2, 512)) = pk;
    }
  }
  __syncthreads();
  // pe2: hid -> pi
  {
    f32x4 acc[2][2];
    lds_gemm_t<2, 2, 8>(hid, fr + FR_PE_W2, w * 2, lane, acc);
    add_bias_act_t<2, 2, true>(acc, pe_b2, w * 32, lane);
    store_lds_t<2, 2, 256>(bufPi, w * 32, lane, acc);
  }
  __syncthreads();
  // ie1 + ia1: shared A-fragments from pi
  {
    bf16x8 x2[2][4];
    lds_load_x<2, 4>(bufPi, lane, x2);
    f32x4 acc[2][2];
    reg_gemm_t<2, 2, 4>(x2, fr + FR_IE_W1, w * 2, lane, acc);
    add_bias_act_t<2, 2, true>(acc, ie_b1, w * 32, lane);
    store_lds_t<2, 2, 256>(hid, w * 32, lane, acc);               // h_ie
    reg_gemm_t<2, 2, 4>(x2, fr + FR_IA_W1, w * 2, lane, acc);
    add_bias_act_t<2, 2, true>(acc, ia_b1, w * 32, lane);
    store_lds_t<2, 2, 256>(hid + 32 * 128, w * 32, lane, acc);    // h_ia
  }
  __syncthreads();
  // ie2: h_ie -> effect (regs; token=lane&15, feat = w*16+q*4+k)
  f32x4 eff[2][1];
  lds_gemm_t<2, 1, 4>(hid, fr + FR_IE_W2, w, lane, eff);
  add_bias_act_t<2, 1, true>(eff, ie_b2, w * 16, lane);
  // ia2 (N=1, VALU): h_ia . ia_W2 -> att
  {
    const int row = t >> 3, s = t & 7;
    const char* hia = (const char*)(hid + 32 * 128);
    float sum = 0.f;
#pragma unroll
    for (int j = 0; j < 16; ++j) {
      int c = s * 16 + j;
      sum += bf2f(*(const ushort_t*)(hia + lds_off(row, c * 2, 256))) * ia_W2[c];
    }
    sum += __shfl_xor(sum, 1);
    sum += __shfl_xor(sum, 2);
    sum += __shfl_xor(sum, 4);
    if (s == 0) att[row] = sigmf(sum + ia_b2[0]);
  }
  __syncthreads();
  // total_effect[g] = sum_{j != i} effect[j] * att[j]   (j = lane&15)
#pragma unroll
  for (int mt = 0; mt < 2; ++mt) {
    const int im = (g0 + mt) & 15;
    const float av = (r == im) ? 0.f : att[mt * 16 + r];
    float v0 = eff[mt][0][0] * av, v1 = eff[mt][0][1] * av;
    float v2 = eff[mt][0][2] * av, v3 = eff[mt][0][3] * av;
#pragma unroll
    for (int d = 1; d < 16; d <<= 1) {
      v0 += __shfl_xor(v0, d);
      v1 += __shfl_xor(v1, d);
      v2 += __shfl_xor(v2, d);
      v3 += __shfl_xor(v3, d);
    }
    if (r == 0) {
      uint2 p;
      p.x = pack2(v0, v1);
      p.y = pack2(v2, v3);
      *(uint2*)(teff + (size_t)(g0 + mt) * 64 + w * 16 + q * 4) = p;
    }
  }
}

// ---------- kernel 4: final merge (fm) -> fp32 output ----------
__global__ __launch_bounds__(256, 2) void fm_kernel(
    const ushort_t* __restrict__ encf, const ushort_t* __restrict__ teff,
    const ushort_t* __restrict__ fr, const float* __restrict__ fm_b1,
    const float* __restrict__ fm_b2, float* __restrict__ out) {
  __shared__ __align__(16) ushort_t bufH[64 * 128];  // 16 KB
  const int t = threadIdx.x, lane = t & 63, w = t >> 6;
  const int r = lane & 15, q = lane >> 4;
  const int rows0 = blockIdx.x * 64;

  bf16x8 x[4][6];
#pragma unroll
  for (int mt = 0; mt < 4; ++mt) {
    const size_t row = rows0 + mt * 16 + r;
#pragma unroll
    for (int ks = 0; ks < 6; ++ks) {
      x[mt][ks] = (ks < 4) ? *(const bf16x8*)(encf + row * 128 + ks * 32 + q * 8)
                           : *(const bf16x8*)(teff + row * 64 + (ks - 4) * 32 + q * 8);
    }
  }
  f32x4 acc[4][2];
  reg_gemm_t<4, 2, 6>(x, fr + FR_FM_W1, w * 2, lane, acc);
  add_bias_act_t<4, 2, true>(acc, fm_b1, w * 32, lane);
  store_lds_t<4, 2, 256>(bufH, w * 32, lane, acc);
  __syncthreads();
  lds_gemm_t<4, 2, 4>(bufH, fr + FR_FM_W2, w * 2, lane, acc);
  add_bias_act_t<4, 2, false>(acc, fm_b2, w * 32, lane);
#pragma unroll
  for (int mt = 0; mt < 4; ++mt)
#pragma unroll
    for (int nt = 0; nt < 2; ++nt)
      *(f32x4*)(out + (size_t)(rows0 + mt * 16 + r) * 128 + w * 32 + nt * 16 + q * 4) =
          acc[mt][nt];
}

// ---------- launcher ----------
extern "C" void kernel_launch(void* const* d_in, const int* in_sizes, int n_in,
                              void* d_out, int out_size, void* d_ws, size_t ws_size,
                              hipStream_t stream) {
  (void)in_sizes; (void)n_in; (void)out_size; (void)ws_size;
  const float* lambda1 = (const float*)d_in[0];
  const float* actions = (const float*)d_in[1];

  ushort_t* ws = (ushort_t*)d_ws;
  ushort_t* encf = ws + OFF_ENCF;
  ushort_t* enc  = ws + OFF_ENC;
  ushort_t* teff = ws + OFF_TEFF;
  ushort_t* fr   = ws + OFF_FR;
  ushort_t* U    = ws + OFF_U;
  ushort_t* V    = ws + OFF_V;

  // weight prep (fragment repack, fp32 -> bf16)
  PrepArgs pa;
  const int src_idx[13] = {2, 4, 8, 10, 14, 12, 18, 20, 22, 24, 26, 30, 32};
  const int foff[13] = {FR_LE_W1, FR_LE_W2, FR_AE_W2, FR_AEF_W1, FR_AAT_W1, FR_AEF_W2,
                        FR_PE_W1, FR_PE_W2, FR_IE_W1, FR_IE_W2, FR_IA_W1, FR_FM_W1, FR_FM_W2};
  const int Ks[13] = {128, 128, 128, 192, 192, 128, 256, 256, 128, 128, 128, 192, 128};
  const int Ns[13] = {128, 128, 64, 128, 128, 128, 256, 128, 128, 64, 128, 128, 128};
  for (int i = 0; i < 13; ++i) {
    pa.d[i].src = (const float*)d_in[src_idx[i]];
    pa.d[i].dst = fr + foff[i];
    pa.d[i].K = Ks[i];
    pa.d[i].N = Ns[i];
  }
  prep_kernel<<<dim3(256, 13), 256, 0, stream>>>(pa);

  enc_kernel<<<512, 256, 0, stream>>>(
      lambda1, actions,
      (const float*)d_in[3], (const float*)d_in[5],              // le_b1, le_b2
      (const float*)d_in[6], (const float*)d_in[7],              // ae_W1, ae_b1
      (const float*)d_in[9],                                     // ae_b2
      (const float*)d_in[11], (const float*)d_in[13],            // aef_b1, aef_b2
      (const float*)d_in[15], (const float*)d_in[16],            // aat_b1, aat_W2
      (const float*)d_in[17],                                    // aat_b2
      fr, encf, enc);

  uv_kernel<<<dim3(512, 2), 256, 0, stream>>>(enc, fr, U, V);

  pair_kernel<<<16384, 256, 0, stream>>>(
      U, V, fr,
      (const float*)d_in[19], (const float*)d_in[21],            // pe_b1, pe_b2
      (const float*)d_in[23], (const float*)d_in[25],            // ie_b1, ie_b2
      (const float*)d_in[27], (const float*)d_in[28],            // ia_b1, ia_W2
      (const float*)d_in[29],                                    // ia_b2
      teff);

  fm_kernel<<<512, 256, 0, stream>>>(encf, teff, fr,
                                     (const float*)d_in[31], (const float*)d_in[33],
                                     (float*)d_out);
}

// Round 11
// 356.407 us; speedup vs baseline: 1.1478x; 1.1000x over previous
//
#include <hip/hip_runtime.h>
#include <hip/hip_bf16.h>

typedef unsigned short ushort_t;
typedef unsigned int uint_t;
typedef short bf16x8 __attribute__((ext_vector_type(8)));
typedef float f32x4 __attribute__((ext_vector_type(4)));

#define MFMA16(a, b, c) __builtin_amdgcn_mfma_f32_16x16x32_bf16((a), (b), (c), 0, 0, 0)

// ---------- numeric helpers ----------
__device__ __forceinline__ ushort_t f2bf(float f) {
  uint_t u = __float_as_uint(f);
  u += 0x7fffu + ((u >> 16) & 1u);  // RNE; inputs finite
  return (ushort_t)(u >> 16);
}
__device__ __forceinline__ float bf2f(ushort_t h) {
  return __uint_as_float(((uint_t)h) << 16);
}
__device__ __forceinline__ uint_t pack2(float lo, float hi) {
  union { __hip_bfloat162 h; uint_t u; } cv;
  cv.h = __float22bfloat162_rn(float2{lo, hi});
  return cv.u;
}
__device__ __forceinline__ uint2 pack4(f32x4 v) {
  uint2 o;
  o.x = pack2(v[0], v[1]);
  o.y = pack2(v[2], v[3]);
  return o;
}
__device__ __forceinline__ float eluf(float x) {
  float e = __expf(x) - 1.0f;
  return x > 0.0f ? x : e;
}
__device__ __forceinline__ float sigmf(float x) {
  return 1.0f / (1.0f + __expf(-x));
}
// LDS byte offset for [row][col] bf16 tiles, XOR swizzle on bits 4-6
__device__ __forceinline__ int lds_off(int row, int colb, int ccb) {
  return row * ccb + (colb ^ ((row & 7) << 4));
}

// ---------- workspace layout (ushort elements) ----------
constexpr size_t OFF_ENCF = 0;        // enc_flat bf16 [32768][128]
constexpr size_t OFF_ENC  = 4194304;  // enc bf16 [32768][128]
constexpr size_t OFF_TEFF = 8388608;  // total_effect bf16 [32768][64]
constexpr size_t OFF_FR   = 10485760; // weight fragments (286720)
constexpr size_t OFF_U    = 10772480; // U bf16 [32768][256]
constexpr size_t OFF_V    = 19161088; // V bf16 [32768][256]  (end 27549696 us = 55.1 MB)

// fragment-layout weight offsets (ushort elements, relative to OFF_FR)
constexpr int FR_LE_W1  = 0;        // 128x128
constexpr int FR_LE_W2  = 16384;    // 128x128
constexpr int FR_AE_W2  = 32768;    // 128x64
constexpr int FR_AEF_W1 = 40960;    // 192x128
constexpr int FR_AAT_W1 = 65536;    // 192x128
constexpr int FR_AEF_W2 = 90112;    // 128x128
constexpr int FR_PE_W1  = 106496;   // 256x256
constexpr int FR_PE_W2  = 172032;   // 256x128
constexpr int FR_IE_W1  = 204800;   // 128x128
constexpr int FR_IE_W2  = 221184;   // 128x64
constexpr int FR_IA_W1  = 229376;   // 128x128
constexpr int FR_FM_W1  = 245760;   // 192x128
constexpr int FR_FM_W2  = 270336;   // 128x128

// ---------- weight prep: fp32 (K,N) row-major -> bf16 MFMA W-fragments ----------
// frag f = ntile*(K/32) + kstep; element idx = f*512 + lane*8 + e
// holds W[kstep*32 + (lane>>4)*8 + e][ntile*16 + (lane&15)]
struct PrepDesc { const float* src; ushort_t* dst; int K; int N; };
struct PrepArgs { PrepDesc d[13]; };

__global__ __launch_bounds__(256) void prep_kernel(PrepArgs a) {
  PrepDesc p = a.d[blockIdx.y];
  int idx = blockIdx.x * 256 + threadIdx.x;
  if (idx >= p.K * p.N) return;
  int e = idx & 7;
  int lane = (idx >> 3) & 63;
  int f = idx >> 9;
  int ksteps = p.K >> 5;
  int kstep = f % ksteps;
  int ntile = f / ksteps;
  int k = kstep * 32 + ((lane >> 4) << 3) + e;
  int n = ntile * 16 + (lane & 15);
  p.dst[idx] = f2bf(p.src[k * p.N + n]);
}

// ---------- transposed GEMM building blocks ----------
// D = Wfrag (A) x Xfrag (B): lane holds out[token = lane&15][feat = (lane>>4)*4 + reg]

template <int MT, int NT, int KS, int KSTR = KS>
__device__ __forceinline__ void reg_gemm_t(const bf16x8 x[MT][KS],
                                           const ushort_t* __restrict__ wfrag,
                                           int ntile0, int lane, f32x4 acc[MT][NT]) {
  const f32x4 z = {0.f, 0.f, 0.f, 0.f};
#pragma unroll
  for (int nt = 0; nt < NT; ++nt) {
#pragma unroll
    for (int m = 0; m < MT; ++m) acc[m][nt] = z;
    const ushort_t* wf = wfrag + (size_t)((ntile0 + nt) * KSTR) * 512 + lane * 8;
#pragma unroll
    for (int ks = 0; ks < KS; ++ks) {
      bf16x8 wfr = *(const bf16x8*)(wf + ks * 512);
#pragma unroll
      for (int m = 0; m < MT; ++m) acc[m][nt] = MFMA16(wfr, x[m][ks], acc[m][nt]);
    }
  }
}

template <int MT, int KS>
__device__ __forceinline__ void lds_load_x(const ushort_t* __restrict__ Abase, int lane,
                                           bf16x8 x[MT][KS]) {
  const int r = lane & 15, q = lane >> 4;
#pragma unroll
  for (int m = 0; m < MT; ++m)
#pragma unroll
    for (int ks = 0; ks < KS; ++ks) {
      int row = m * 16 + r;
      x[m][ks] = *(const bf16x8*)((const char*)Abase + lds_off(row, ks * 64 + q * 16, KS * 64));
    }
}

template <int MT, int NT, int KS>
__device__ __forceinline__ void lds_gemm_t(const ushort_t* __restrict__ Abase,
                                           const ushort_t* __restrict__ wfrag,
                                           int ntile0, int lane, f32x4 acc[MT][NT]) {
  bf16x8 x[MT][KS];
  lds_load_x<MT, KS>(Abase, lane, x);
  reg_gemm_t<MT, NT, KS>(x, wfrag, ntile0, lane, acc);
}

template <int MT, int NT, bool ELU>
__device__ __forceinline__ void add_bias_act_t(f32x4 acc[MT][NT], const float* __restrict__ bias,
                                               int col0, int lane) {
  const int q = lane >> 4;
#pragma unroll
  for (int nt = 0; nt < NT; ++nt) {
    f32x4 bv = *(const f32x4*)(bias + col0 + nt * 16 + q * 4);
#pragma unroll
    for (int m = 0; m < MT; ++m)
#pragma unroll
      for (int k = 0; k < 4; ++k) {
        float v = acc[m][nt][k] + bv[k];
        acc[m][nt][k] = ELU ? eluf(v) : v;
      }
  }
}

template <int MT, int NT, int CCB>  // CCB = LDS row stride in bytes
__device__ __forceinline__ void store_lds_t(ushort_t* Dbase, int col0, int lane,
                                            const f32x4 acc[MT][NT]) {
  const int r = lane & 15, q = lane >> 4;
#pragma unroll
  for (int m = 0; m < MT; ++m) {
    const int row = m * 16 + r;
#pragma unroll
    for (int nt = 0; nt < NT; ++nt) {
      int colb = (col0 + nt * 16 + q * 4) * 2;
      *(uint2*)((char*)Dbase + lds_off(row, colb, CCB)) = pack4(acc[m][nt]);
    }
  }
}

template <int MT, int NT>
__device__ __forceinline__ void store_global_t(ushort_t* __restrict__ G, int row0, int ncols,
                                               int col0, int lane, const f32x4 acc[MT][NT]) {
  const int r = lane & 15, q = lane >> 4;
#pragma unroll
  for (int m = 0; m < MT; ++m)
#pragma unroll
    for (int nt = 0; nt < NT; ++nt)
      *(uint2*)(G + (size_t)(row0 + m * 16 + r) * ncols + col0 + nt * 16 + q * 4) =
          pack4(acc[m][nt]);
}

// D-layout (uint2-packed, feats nt*16+q*4+{0..3}) -> B-frag x[ks] (k = ks*32+q*8+e).
// lo uint2 (e0-3) from lane (2(q&1))*16+r, hi (e4-7) from +16; nt = 2ks+(q>>1).
__device__ __forceinline__ void transpose_frags(const uint2 P[8], int lane, bf16x8 x[4]) {
  const int q = lane >> 4;
  const int srcA = ((q & 1) * 2) * 16 + (lane & 15);
  const int srcB = srcA + 16;
  const bool hiSel = (q >> 1) & 1;
#pragma unroll
  for (int ks = 0; ks < 4; ++ks) {
    uint_t l0x = __shfl((int)P[2 * ks].x, srcA), l0y = __shfl((int)P[2 * ks].y, srcA);
    uint_t l1x = __shfl((int)P[2 * ks + 1].x, srcA), l1y = __shfl((int)P[2 * ks + 1].y, srcA);
    uint_t h0x = __shfl((int)P[2 * ks].x, srcB), h0y = __shfl((int)P[2 * ks].y, srcB);
    uint_t h1x = __shfl((int)P[2 * ks + 1].x, srcB), h1y = __shfl((int)P[2 * ks + 1].y, srcB);
    uint4 v;
    v.x = hiSel ? l1x : l0x;
    v.y = hiSel ? l1y : l0y;
    v.z = hiSel ? h1x : h0x;
    v.w = hiSel ? h1y : h0y;
    x[ks] = *(bf16x8*)&v;
  }
}

// ---------- kernel 1: per-object encoder (le, ae, aef, aat -> enc_flat, enc) ----------
__global__ __launch_bounds__(256, 2) void enc_kernel(
    const float* __restrict__ lambda1, const float* __restrict__ actions,
    const float* __restrict__ le_b1, const float* __restrict__ le_b2,
    const float* __restrict__ ae_W1, const float* __restrict__ ae_b1,
    const float* __restrict__ ae_b2, const float* __restrict__ aef_b1,
    const float* __restrict__ aef_b2, const float* __restrict__ aat_b1,
    const float* __restrict__ aat_W2, const float* __restrict__ aat_b2,
    const ushort_t* __restrict__ fr, ushort_t* __restrict__ encf, ushort_t* __restrict__ enc) {
  __shared__ __align__(16) ushort_t bufA[64 * 128];  // 16 KB
  __shared__ __align__(16) ushort_t bufB[64 * 128];  // 16 KB
  __shared__ __align__(16) ushort_t la[64 * 192];    // 24 KB
  __shared__ float att[64];

  const int t = threadIdx.x, lane = t & 63, w = t >> 6;
  const int r = lane & 15, q = lane >> 4;
  const int rows0 = blockIdx.x * 64;

  // stage lambda1 tile -> bufA (bf16, swizzled, packed 8B writes)
  {
    const int row = t >> 2, c0 = (t & 3) * 32;
    const float4* src = (const float4*)(lambda1 + (size_t)(rows0 + row) * 128 + c0);
#pragma unroll
    for (int j = 0; j < 8; ++j) {
      float4 v = src[j];
      f32x4 vv = {v.x, v.y, v.z, v.w};
      *(uint2*)((char*)bufA + lds_off(row, (c0 + j * 4) * 2, 256)) = pack4(vv);
    }
  }
  __syncthreads();

  f32x4 acc2[4][2];
  // le layer 1: bufA -> bufB
  lds_gemm_t<4, 2, 4>(bufA, fr + FR_LE_W1, w * 2, lane, acc2);
  add_bias_act_t<4, 2, true>(acc2, le_b1, w * 32, lane);
  store_lds_t<4, 2, 256>(bufB, w * 32, lane, acc2);
  __syncthreads();
  // le layer 2: bufB -> la[:,0:128] + global enc_flat
  lds_gemm_t<4, 2, 4>(bufB, fr + FR_LE_W2, w * 2, lane, acc2);
  add_bias_act_t<4, 2, true>(acc2, le_b2, w * 32, lane);
  store_lds_t<4, 2, 384>(la, w * 32, lane, acc2);
  store_global_t<4, 2>(encf, rows0, 128, w * 32, lane, acc2);
  // ae layer 1 (K=6, VALU): actions -> bufA (bufA free after prior sync)
  {
    const int row = t >> 2, c0 = (t & 3) * 32;
    float a6[6];
#pragma unroll
    for (int k2 = 0; k2 < 6; ++k2) a6[k2] = actions[(size_t)(rows0 + row) * 6 + k2];
#pragma unroll
    for (int j = 0; j < 16; ++j) {
      int c = c0 + j * 2;
      float s0 = ae_b1[c], s1 = ae_b1[c + 1];
#pragma unroll
      for (int k2 = 0; k2 < 6; ++k2) {
        s0 += a6[k2] * ae_W1[k2 * 128 + c];
        s1 += a6[k2] * ae_W1[k2 * 128 + c + 1];
      }
      *(uint_t*)((char*)bufA + lds_off(row, c * 2, 256)) = pack2(eluf(s0), eluf(s1));
    }
  }
  __syncthreads();
  // ae layer 2: bufA -> la[:,128:192]
  {
    f32x4 acc1[4][1];
    lds_gemm_t<4, 1, 4>(bufA, fr + FR_AE_W2, w, lane, acc1);
    add_bias_act_t<4, 1, true>(acc1, ae_b2, w * 16, lane);
    store_lds_t<4, 1, 384>(la, 128 + w * 16, lane, acc1);
  }
  __syncthreads();
  // aef layer 1 + aat layer 1: shared A-fragments from la
  {
    bf16x8 xla[4][6];
    lds_load_x<4, 6>(la, lane, xla);
    reg_gemm_t<4, 2, 6>(xla, fr + FR_AEF_W1, w * 2, lane, acc2);
    add_bias_act_t<4, 2, true>(acc2, aef_b1, w * 32, lane);
    store_lds_t<4, 2, 256>(bufA, w * 32, lane, acc2);
    reg_gemm_t<4, 2, 6>(xla, fr + FR_AAT_W1, w * 2, lane, acc2);
    add_bias_act_t<4, 2, true>(acc2, aat_b1, w * 32, lane);
    store_lds_t<4, 2, 256>(bufB, w * 32, lane, acc2);
  }
  __syncthreads();
  // aef layer 2: bufA -> regs (a_eff)
  lds_gemm_t<4, 2, 4>(bufA, fr + FR_AEF_W2, w * 2, lane, acc2);
  add_bias_act_t<4, 2, true>(acc2, aef_b2, w * 32, lane);
  // aat layer 2 (N=1, VALU): bufB -> att
  {
    const int row = t >> 2, s = t & 3;
    float sum = 0.f;
#pragma unroll
    for (int j = 0; j < 32; ++j) {
      int c = s * 32 + j;
      sum += bf2f(*(const ushort_t*)((const char*)bufB + lds_off(row, c * 2, 256))) * aat_W2[c];
    }
    sum += __shfl_xor(sum, 1);
    sum += __shfl_xor(sum, 2);
    if (s == 0) att[row] = sigmf(sum + aat_b2[0]);
  }
  __syncthreads();
  // enc = a_eff * a_att -> global (packed 8B stores)
#pragma unroll
  for (int mt = 0; mt < 4; ++mt) {
    float av = att[mt * 16 + r];
#pragma unroll
    for (int nt = 0; nt < 2; ++nt) {
      f32x4 sv = acc2[mt][nt];
      sv[0] *= av; sv[1] *= av; sv[2] *= av; sv[3] *= av;
      *(uint2*)(enc + (size_t)(rows0 + mt * 16 + r) * 128 + w * 32 + nt * 16 + q * 4) = pack4(sv);
    }
  }
}

// ---------- kernel 2: U/V projections  U = enc @ peW1[:128], V = enc @ peW1[128:] ----------
__global__ __launch_bounds__(256, 2) void uv_kernel(const ushort_t* __restrict__ enc,
                                                    const ushort_t* __restrict__ fr,
                                                    ushort_t* __restrict__ U,
                                                    ushort_t* __restrict__ V) {
  const int t = threadIdx.x, lane = t & 63, w = t >> 6;
  const int r = lane & 15, q = lane >> 4;
  const int rows0 = blockIdx.x * 64;
  const int half = blockIdx.y;  // 0 = U (k rows 0-127), 1 = V (k rows 128-255)

  bf16x8 x[4][4];
#pragma unroll
  for (int m = 0; m < 4; ++m)
#pragma unroll
    for (int ks = 0; ks < 4; ++ks)
      x[m][ks] = *(const bf16x8*)(enc + (size_t)(rows0 + m * 16 + r) * 128 + ks * 32 + q * 8);

  f32x4 acc[4][4];
  // KSTR=8: pe_W1 has K=256 (8 ksteps per ntile); offset ks0 = half*4 folded into pointer
  reg_gemm_t<4, 4, 4, 8>(x, fr + FR_PE_W1 + half * 4 * 512, w * 4, lane, acc);
  store_global_t<4, 4>(half ? V : U, rows0, 256, w * 64, lane, acc);
}

// ---------- kernel 3: FUSED pairwise stage — no LDS, no barriers ----------
// 1 wave = 2 whole (b,i) groups; hidden built into B-frags; chain in registers.
__global__ __launch_bounds__(256, 2) void pair_kernel(
    const ushort_t* __restrict__ U, const ushort_t* __restrict__ V,
    const ushort_t* __restrict__ fr,
    const float* __restrict__ pe_b1, const float* __restrict__ pe_b2,
    const float* __restrict__ ie_b1, const float* __restrict__ ie_b2,
    const float* __restrict__ ia_b1, const float* __restrict__ ia_W2,
    const float* __restrict__ ia_b2, ushort_t* __restrict__ teff) {
  const int t = threadIdx.x, lane = t & 63, w = t >> 6;
  const int r = lane & 15, q = lane >> 4;
  // pair-preserving bijective XCD swizzle (4096 blocks = 2048 pairs, 256 pairs/XCD);
  // the two blocks of one batch land on the same XCD for U/V L2 reuse.
  const int pid = blockIdx.x >> 1, hh = blockIdx.x & 1;
  const int blk = ((pid & 7) * 256 + (pid >> 3)) * 2 + hh;
  const int g0 = blk * 8 + w * 2;  // this wave's first group
  const int b = g0 >> 4;

  // --- hidden B-frags: hf[m][ks] holds elu(U[i_m]+V[j=r]+b1)[k=ks*32+q*8+e] ---
  bf16x8 hf[2][8];
  {
    const ushort_t* Vrow = V + (size_t)(b * 16 + r) * 256;
    const ushort_t* Ur0 = U + (size_t)(b * 16 + ((g0 + 0) & 15)) * 256;
    const ushort_t* Ur1 = U + (size_t)(b * 16 + ((g0 + 1) & 15)) * 256;
#pragma unroll
    for (int ks = 0; ks < 8; ++ks) {
      const int k0 = ks * 32 + q * 8;
      bf16x8 vv = *(const bf16x8*)(Vrow + k0);
      bf16x8 u0 = *(const bf16x8*)(Ur0 + k0);
      bf16x8 u1 = *(const bf16x8*)(Ur1 + k0);
      f32x4 b0 = *(const f32x4*)(pe_b1 + k0);
      f32x4 b1 = *(const f32x4*)(pe_b1 + k0 + 4);
      float h0[8], h1[8];
#pragma unroll
      for (int e = 0; e < 8; ++e) {
        float vb = bf2f((ushort_t)vv[e]) + ((e < 4) ? b0[e] : b1[e - 4]);
        h0[e] = eluf(bf2f((ushort_t)u0[e]) + vb);
        h1[e] = eluf(bf2f((ushort_t)u1[e]) + vb);
      }
      uint4 p0, p1;
      p0.x = pack2(h0[0], h0[1]); p0.y = pack2(h0[2], h0[3]);
      p0.z = pack2(h0[4], h0[5]); p0.w = pack2(h0[6], h0[7]);
      p1.x = pack2(h1[0], h1[1]); p1.y = pack2(h1[2], h1[3]);
      p1.z = pack2(h1[4], h1[5]); p1.w = pack2(h1[6], h1[7]);
      hf[0][ks] = *(bf16x8*)&p0;
      hf[1][ks] = *(bf16x8*)&p1;
    }
  }

  const f32x4 z = {0.f, 0.f, 0.f, 0.f};
  // --- pe2: K=256, N=128 -> P (packed D-layout) ---
  uint2 P[2][8];
#pragma unroll
  for (int nt = 0; nt < 8; ++nt) {
    f32x4 a0 = z, a1 = z;
    const ushort_t* wf = fr + FR_PE_W2 + (size_t)(nt * 8) * 512 + lane * 8;
#pragma unroll
    for (int ks = 0; ks < 8; ++ks) {
      bf16x8 wfr = *(const bf16x8*)(wf + ks * 512);
      a0 = MFMA16(wfr, hf[0][ks], a0);
      a1 = MFMA16(wfr, hf[1][ks], a1);
    }
    f32x4 bv = *(const f32x4*)(pe_b2 + nt * 16 + q * 4);
#pragma unroll
    for (int k = 0; k < 4; ++k) {
      a0[k] = eluf(a0[k] + bv[k]);
      a1[k] = eluf(a1[k] + bv[k]);
    }
    P[0][nt] = pack4(a0);
    P[1][nt] = pack4(a1);
  }

  // --- transpose P -> x1 (pi as B-frags, K=128) ---
  bf16x8 x1[2][4];
  transpose_frags(P[0], lane, x1[0]);
  transpose_frags(P[1], lane, x1[1]);

  // --- ie1 (-> Pe) + ia1 (-> on-the-fly ia2 dot) ---
  uint2 Pe[2][8];
  float attp0 = 0.f, attp1 = 0.f;
#pragma unroll
  for (int nt = 0; nt < 8; ++nt) {
    f32x4 a0 = z, a1 = z, c0 = z, c1 = z;
    const ushort_t* wfe = fr + FR_IE_W1 + (size_t)(nt * 4) * 512 + lane * 8;
    const ushort_t* wfa = fr + FR_IA_W1 + (size_t)(nt * 4) * 512 + lane * 8;
#pragma unroll
    for (int ks = 0; ks < 4; ++ks) {
      bf16x8 we = *(const bf16x8*)(wfe + ks * 512);
      bf16x8 wa = *(const bf16x8*)(wfa + ks * 512);
      a0 = MFMA16(we, x1[0][ks], a0);
      a1 = MFMA16(we, x1[1][ks], a1);
      c0 = MFMA16(wa, x1[0][ks], c0);
      c1 = MFMA16(wa, x1[1][ks], c1);
    }
    f32x4 be = *(const f32x4*)(ie_b1 + nt * 16 + q * 4);
    f32x4 ba = *(const f32x4*)(ia_b1 + nt * 16 + q * 4);
    f32x4 w2 = *(const f32x4*)(ia_W2 + nt * 16 + q * 4);
#pragma unroll
    for (int k = 0; k < 4; ++k) {
      a0[k] = eluf(a0[k] + be[k]);
      a1[k] = eluf(a1[k] + be[k]);
      attp0 += eluf(c0[k] + ba[k]) * w2[k];
      attp1 += eluf(c1[k] + ba[k]) * w2[k];
    }
    Pe[0][nt] = pack4(a0);
    Pe[1][nt] = pack4(a1);
  }
  // reduce ia2 dot over q (lanes 16/32 apart); all lanes keep att of token (m, r)
  attp0 += __shfl_xor(attp0, 16); attp0 += __shfl_xor(attp0, 32);
  attp1 += __shfl_xor(attp1, 16); attp1 += __shfl_xor(attp1, 32);
  const float att0 = sigmf(attp0 + ia_b2[0]);
  const float att1 = sigmf(attp1 + ia_b2[0]);

  // --- transpose Pe -> x2 (h_ie as B-frags, K=128) ---
  bf16x8 x2[2][4];
  transpose_frags(Pe[0], lane, x2[0]);
  transpose_frags(Pe[1], lane, x2[1]);

  // --- ie2: K=128, N=64 -> effect; weight by att (masked j==i); reduce over j=r ---
  const float av0 = (r == ((g0 + 0) & 15)) ? 0.f : att0;
  const float av1 = (r == ((g0 + 1) & 15)) ? 0.f : att1;
#pragma unroll
  for (int nt = 0; nt < 4; ++nt) {
    f32x4 a0 = z, a1 = z;
    const ushort_t* wf = fr + FR_IE_W2 + (size_t)(nt * 4) * 512 + lane * 8;
#pragma unroll
    for (int ks = 0; ks < 4; ++ks) {
      bf16x8 wfr = *(const bf16x8*)(wf + ks * 512);
      a0 = MFMA16(wfr, x2[0][ks], a0);
      a1 = MFMA16(wfr, x2[1][ks], a1);
    }
    f32x4 bv = *(const f32x4*)(ie_b2 + nt * 16 + q * 4);
#pragma unroll
    for (int k = 0; k < 4; ++k) {
      a0[k] = eluf(a0[k] + bv[k]) * av0;
      a1[k] = eluf(a1[k] + bv[k]) * av1;
    }
#pragma unroll
    for (int d = 1; d < 16; d <<= 1) {
#pragma unroll
      for (int k = 0; k < 4; ++k) {
        a0[k] += __shfl_xor(a0[k], d);
        a1[k] += __shfl_xor(a1[k], d);
      }
    }
    if (r == 0) {
      *(uint_t*)(teff + (size_t)(g0 + 0) * 64 + nt * 16 + q * 4) = pack2(a0[0], a0[1]);
      *(uint_t*)(teff + (size_t)(g0 + 0) * 64 + nt * 16 + q * 4 + 2) = pack2(a0[2], a0[3]);
      *(uint_t*)(teff + (size_t)(g0 + 1) * 64 + nt * 16 + q * 4) = pack2(a1[0], a1[1]);
      *(uint_t*)(teff + (size_t)(g0 + 1) * 64 + nt * 16 + q * 4 + 2) = pack2(a1[2], a1[3]);
    }
  }
}

// ---------- kernel 4: final merge (fm) -> fp32 output ----------
__global__ __launch_bounds__(256, 2) void fm_kernel(
    const ushort_t* __restrict__ encf, const ushort_t* __restrict__ teff,
    const ushort_t* __restrict__ fr, const float* __restrict__ fm_b1,
    const float* __restrict__ fm_b2, float* __restrict__ out) {
  __shared__ __align__(16) ushort_t bufH[64 * 128];  // 16 KB
  const int t = threadIdx.x, lane = t & 63, w = t >> 6;
  const int r = lane & 15, q = lane >> 4;
  const int rows0 = blockIdx.x * 64;

  bf16x8 x[4][6];
#pragma unroll
  for (int mt = 0; mt < 4; ++mt) {
    const size_t row = rows0 + mt * 16 + r;
#pragma unroll
    for (int ks = 0; ks < 6; ++ks) {
      x[mt][ks] = (ks < 4) ? *(const bf16x8*)(encf + row * 128 + ks * 32 + q * 8)
                           : *(const bf16x8*)(teff + row * 64 + (ks - 4) * 32 + q * 8);
    }
  }
  f32x4 acc[4][2];
  reg_gemm_t<4, 2, 6>(x, fr + FR_FM_W1, w * 2, lane, acc);
  add_bias_act_t<4, 2, true>(acc, fm_b1, w * 32, lane);
  store_lds_t<4, 2, 256>(bufH, w * 32, lane, acc);
  __syncthreads();
  lds_gemm_t<4, 2, 4>(bufH, fr + FR_FM_W2, w * 2, lane, acc);
  add_bias_act_t<4, 2, false>(acc, fm_b2, w * 32, lane);
#pragma unroll
  for (int mt = 0; mt < 4; ++mt)
#pragma unroll
    for (int nt = 0; nt < 2; ++nt)
      *(f32x4*)(out + (size_t)(rows0 + mt * 16 + r) * 128 + w * 32 + nt * 16 + q * 4) =
          acc[mt][nt];
}

// ---------- launcher ----------
extern "C" void kernel_launch(void* const* d_in, const int* in_sizes, int n_in,
                              void* d_out, int out_size, void* d_ws, size_t ws_size,
                              hipStream_t stream) {
  (void)in_sizes; (void)n_in; (void)out_size; (void)ws_size;
  const float* lambda1 = (const float*)d_in[0];
  const float* actions = (const float*)d_in[1];

  ushort_t* ws = (ushort_t*)d_ws;
  ushort_t* encf = ws + OFF_ENCF;
  ushort_t* enc  = ws + OFF_ENC;
  ushort_t* teff = ws + OFF_TEFF;
  ushort_t* fr   = ws + OFF_FR;
  ushort_t* U    = ws + OFF_U;
  ushort_t* V    = ws + OFF_V;

  // weight prep (fragment repack, fp32 -> bf16)
  PrepArgs pa;
  const int src_idx[13] = {2, 4, 8, 10, 14, 12, 18, 20, 22, 24, 26, 30, 32};
  const int foff[13] = {FR_LE_W1, FR_LE_W2, FR_AE_W2, FR_AEF_W1, FR_AAT_W1, FR_AEF_W2,
                        FR_PE_W1, FR_PE_W2, FR_IE_W1, FR_IE_W2, FR_IA_W1, FR_FM_W1, FR_FM_W2};
  const int Ks[13] = {128, 128, 128, 192, 192, 128, 256, 256, 128, 128, 128, 192, 128};
  const int Ns[13] = {128, 128, 64, 128, 128, 128, 256, 128, 128, 64, 128, 128, 128};
  for (int i = 0; i < 13; ++i) {
    pa.d[i].src = (const float*)d_in[src_idx[i]];
    pa.d[i].dst = fr + foff[i];
    pa.d[i].K = Ks[i];
    pa.d[i].N = Ns[i];
  }
  prep_kernel<<<dim3(256, 13), 256, 0, stream>>>(pa);

  enc_kernel<<<512, 256, 0, stream>>>(
      lambda1, actions,
      (const float*)d_in[3], (const float*)d_in[5],              // le_b1, le_b2
      (const float*)d_in[6], (const float*)d_in[7],              // ae_W1, ae_b1
      (const float*)d_in[9],                                     // ae_b2
      (const float*)d_in[11], (const float*)d_in[13],            // aef_b1, aef_b2
      (const float*)d_in[15], (const float*)d_in[16],            // aat_b1, aat_W2
      (const float*)d_in[17],                                    // aat_b2
      fr, encf, enc);

  uv_kernel<<<dim3(512, 2), 256, 0, stream>>>(enc, fr, U, V);

  pair_kernel<<<4096, 256, 0, stream>>>(
      U, V, fr,
      (const float*)d_in[19], (const float*)d_in[21],            // pe_b1, pe_b2
      (const float*)d_in[23], (const float*)d_in[25],            // ie_b1, ie_b2
      (const float*)d_in[27], (const float*)d_in[28],            // ia_b1, ia_W2
      (const float*)d_in[29],                                    // ia_b2
      teff);

  fm_kernel<<<512, 256, 0, stream>>>(encf, teff, fr,
                                     (const float*)d_in[31], (const float*)d_in[33],
                                     (float*)d_out);
}